// Round 6
// baseline (305.986 us; speedup 1.0000x reference)
//
#include <hip/hip_runtime.h>
#include <hip/hip_bf16.h>

// ---------------------------------------------------------------------------
// CausalMultiHeadedSelfAttention on gfx950.
// R6: attn = R3 single-buffer skeleton + fused dual-q-tile step (K/V frags
// read ONCE for both tiles; two P buffers, one fence) -> LDS traffic -40%.
// gemm_qk epilogue uses fused float2 cos/sin table (half the table loads).
// Schraudolph P + MFMA-l kept from R5. gemm_tile (V/out) kept from R4.
// ---------------------------------------------------------------------------

typedef __bf16 bf16;
typedef __bf16 bf16x8 __attribute__((ext_vector_type(8)));
typedef __bf16 bf16x4 __attribute__((ext_vector_type(4)));
typedef float f32x4 __attribute__((ext_vector_type(4)));

#define LOG2E 1.4426950408889634f
// Schraudolph: p = exp(s/8 - 16) = 2^t, bits(p) ~= int(2^23*(t + 126.9427)).
// Q pre-scaled by QSCALE so QK-MFMA emits t' = 2^23*t; acc seeded with
// SEXP_SEED. t' in [7.7e8, 1.1e9]; masked entries t'=0 -> p=+0.0 exactly.
#define QSCALE (0.125f * LOG2E * 8388608.0f)
#define SEXP_SEED ((126.94269504f - 16.0f * LOG2E) * 8388608.0f)

__device__ __forceinline__ void async16(const void* g, void* l) {
  __builtin_amdgcn_global_load_lds(
      (const __attribute__((address_space(1))) void*)g,
      (__attribute__((address_space(3))) void*)l, 16, 0, 0);
}

#define MFMA16(a, b, c) __builtin_amdgcn_mfma_f32_16x16x32_bf16(a, b, c, 0, 0, 0)

// ---------------------------------------------------------------------------
// fused fp32 -> bf16 cast for x + 4 weights + cos/sin float2 fusion.
// ---------------------------------------------------------------------------
__global__ void cast_all_kernel(const float* __restrict__ x,
                                const float* __restrict__ wq,
                                const float* __restrict__ wk,
                                const float* __restrict__ wv,
                                const float* __restrict__ wo,
                                const float* __restrict__ cosT,
                                const float* __restrict__ sinT,
                                bf16* __restrict__ xb, bf16* __restrict__ wb,
                                float2* __restrict__ csT) {
  int i = blockIdx.x * blockDim.x + threadIdx.x;
  if (i >= 3145728) {  // cos/sin fusion: 65536 pairs
    int j = i - 3145728;
    float2 cs;
    cs.x = cosT[j];
    cs.y = sinT[j];
    csT[j] = cs;
    return;
  }
  const float* src;
  bf16* dst;
  long o;
  if (i < 2097152) {
    src = x; dst = xb; o = i;
  } else {
    long j = i - 2097152;
    int w = (int)(j >> 18);
    o = j & 262143;
    src = (w == 0) ? wq : (w == 1) ? wk : (w == 2) ? wv : wo;
    dst = wb + (long)w * 1048576;
  }
  float4 v = reinterpret_cast<const float4*>(src)[o];
  bf16x4 out;
  out.x = (bf16)v.x; out.y = (bf16)v.y; out.z = (bf16)v.z; out.w = (bf16)v.w;
  *reinterpret_cast<bf16x4*>(dst + o * 4) = out;
}

// ---------------------------------------------------------------------------
// Generic bt-GEMM tile: C[m][n] = sum_k A[m][k]*B[n][k].  TM x TN block tile,
// BK=32, XOR-swizzled staging.
// EPI 1: bf16 V^T (b,h,d,s) layout.  EPI 2: fp32 row-major (M,N).
// ---------------------------------------------------------------------------
template <int EPI, int TM, int TN>
__global__ __launch_bounds__(256) void gemm_tile(const bf16* __restrict__ A,
                                                 const bf16* __restrict__ B,
                                                 void* __restrict__ C, int N,
                                                 int K) {
  constexpr int WM = TM / 64;
  constexpr int WN = 4 / WM;
  constexpr int CW = TN / WN;
  constexpr int NT = CW / 16;
  constexpr int ROUNDS = (TM + TN) / 64;
  __shared__ __align__(16) bf16 As[TM * 32];
  __shared__ __align__(16) bf16 Bs[TN * 32];
  const int tid = threadIdx.x;
  const int wid = tid >> 6, lane = tid & 63;
  const int quad = lane >> 4, l15 = lane & 15;
  const int waveM = wid / WN, waveN = wid % WN;
  const int bm = blockIdx.y, bn = blockIdx.x;

  f32x4 acc[4][NT] = {};

  const bf16* Ag = A + (long)bm * TM * K;
  const bf16* Bg = B + (long)bn * TN * K;

  for (int k0 = 0; k0 < K; k0 += 32) {
#pragma unroll
    for (int ri = 0; ri < ROUNDS; ++ri) {
      int c = ri * 256 + tid;
      int g = ri * 256 + (wid << 6);
      bool isA = g < TM * 4;
      int cl = isA ? c : c - TM * 4;
      int r = cl >> 2;
      int col = ((cl & 3) ^ (r & 3)) << 3;
      const bf16* src = (isA ? Ag : Bg) + (long)r * K + k0 + col;
      char* dst = isA ? ((char*)As + (long)g * 16)
                      : ((char*)Bs + (long)(g - TM * 4) * 16);
      async16(src, dst);
    }
    __syncthreads();
    bf16x8 af[4], bfr[NT];
#pragma unroll
    for (int t = 0; t < 4; ++t) {
      int rowA = waveM * 64 + t * 16 + l15;
      af[t] = *(const bf16x8*)(As + rowA * 32 + ((quad ^ (rowA & 3)) << 3));
    }
#pragma unroll
    for (int t = 0; t < NT; ++t) {
      int rowB = waveN * CW + t * 16 + l15;
      bfr[t] = *(const bf16x8*)(Bs + rowB * 32 + ((quad ^ (rowB & 3)) << 3));
    }
#pragma unroll
    for (int mt = 0; mt < 4; ++mt)
#pragma unroll
      for (int nt = 0; nt < NT; ++nt)
        acc[mt][nt] = MFMA16(af[mt], bfr[nt], acc[mt][nt]);
    __syncthreads();
  }

#pragma unroll
  for (int mt = 0; mt < 4; ++mt)
#pragma unroll
    for (int nt = 0; nt < NT; ++nt)
#pragma unroll
      for (int r = 0; r < 4; ++r) {
        int row = bm * TM + waveM * 64 + mt * 16 + quad * 4 + r;
        int col = bn * TN + waveN * CW + nt * 16 + l15;
        float v = acc[mt][nt][r];
        if (EPI == 1) {
          long off = (long)(col >> 11) * 2097152 + (long)row * 2048 +
                     (col & 2047);
          ((bf16*)C)[off] = (bf16)v;
        } else {
          ((float*)C)[(long)row * N + col] = v;
        }
      }
}

// ---------------------------------------------------------------------------
// Fused Q+K projection GEMM with RoPE epilogue (fused float2 cos/sin table).
// Q half pre-scaled by QSCALE (Schraudolph domain).
// ---------------------------------------------------------------------------
__global__ __launch_bounds__(256) void gemm_qk(const bf16* __restrict__ A,
                                               const bf16* __restrict__ B,
                                               bf16* __restrict__ QK,
                                               const float2* __restrict__ csT,
                                               int K) {
  __shared__ __align__(16) bf16 As[128 * 32];
  __shared__ __align__(16) bf16 Bs[128 * 32];
  const int tid = threadIdx.x;
  const int wid = tid >> 6, lane = tid & 63;
  const int quad = lane >> 4, l15 = lane & 15;
  const int waveM = wid >> 1, waveN = wid & 1;
  const int bm = blockIdx.y, bn = blockIdx.x;

  f32x4 acc[4][4] = {};
  const bf16* Ag = A + (long)bm * 128 * K;
  const bf16* Bg = B + (long)bn * 128 * K;

  for (int k0 = 0; k0 < K; k0 += 32) {
#pragma unroll
    for (int it = 0; it < 2; ++it) {
      int chunk = it * 256 + tid;
      int r = chunk >> 2;
      int c = ((chunk & 3) ^ (r & 3)) << 3;
      int ldsbase = (it * 256 + wid * 64) * 16;
      async16(Ag + (long)r * K + k0 + c, (char*)As + ldsbase);
      async16(Bg + (long)r * K + k0 + c, (char*)Bs + ldsbase);
    }
    __syncthreads();
    bf16x8 af[4], bfr[4];
#pragma unroll
    for (int t = 0; t < 4; ++t) {
      int rowA = waveM * 64 + t * 16 + l15;
      af[t] = *(const bf16x8*)(As + rowA * 32 + ((quad ^ (rowA & 3)) << 3));
    }
#pragma unroll
    for (int t = 0; t < 4; ++t) {
      int rowB = waveN * 64 + t * 16 + l15;
      bfr[t] = *(const bf16x8*)(Bs + rowB * 32 + ((quad ^ (rowB & 3)) << 3));
    }
#pragma unroll
    for (int mt = 0; mt < 4; ++mt)
#pragma unroll
      for (int nt = 0; nt < 4; ++nt)
        acc[mt][nt] = MFMA16(af[mt], bfr[nt], acc[mt][nt]);
    __syncthreads();
  }

  // RoPE epilogue; bn<8 -> Q half: apply Schraudolph pre-scale.
  const float qsc = (bn < 8) ? QSCALE : 1.0f;
#pragma unroll
  for (int mt = 0; mt < 4; ++mt)
#pragma unroll
    for (int nt = 0; nt < 4; ++nt)
#pragma unroll
      for (int r = 0; r < 4; ++r) {
        int row = bm * 128 + waveM * 64 + mt * 16 + quad * 4 + r;  // token
        int col = bn * 128 + waveN * 64 + nt * 16 + l15;           // 0..2047
        float v = acc[mt][nt][r];
        float pr = __shfl_xor(v, 1);
        int d = col & 63;
        float2 cs = csT[(row & 2047) * 32 + (d >> 1)];
        float o = (col & 1) ? (v * cs.x + pr * cs.y) : (v * cs.x - pr * cs.y);
        o *= qsc;
        long off = (long)(col >> 10) * 8388608 +
                   (long)(((row >> 11) << 4) + ((col >> 6) & 15)) * 131072 +
                   (long)(row & 2047) * 64 + d;
        QK[off] = (bf16)o;
      }
}

// ---------------------------------------------------------------------------
// Flash attention, causal, paired q-tiles {p, 31-p}, single-buffer staging
// (R3 skeleton), FUSED dual-tile step: K/V fragments read once for both
// tiles; two P buffers share one lgkmcnt fence.  Schraudolph P, MFMA-l.
// LDS = 8K(Ks)+8K(Vs)+22528(Ps) = 38912 B -> 4 blocks/CU.
// ---------------------------------------------------------------------------
__global__ __launch_bounds__(256, 4) void attn_kernel(
    const bf16* __restrict__ Q, const bf16* __restrict__ Kg,
    const bf16* __restrict__ VT, bf16* __restrict__ Out) {
  __shared__ __align__(16) bf16 Ks[64 * 64];
  __shared__ __align__(16) bf16 Vs[64 * 64];
  __shared__ __align__(16) bf16 Ps[4][2][16 * 88];
  const int tid = threadIdx.x, wid = tid >> 6, lane = tid & 63;
  const int quad = lane >> 4, l15 = lane & 15;
  const int p = blockIdx.x, bh = blockIdx.y;
  const int q0t = p, q1t = 31 - p;
  const bf16* Qb = Q + (long)bh * 131072;
  const bf16* Kb = Kg + (long)bh * 131072;
  const bf16* Vb = VT + (long)bh * 131072;
  bf16* Pw1 = &Ps[wid][0][0];
  bf16* Pw0 = &Ps[wid][1][0];
  const int qloc = wid * 16 + l15;
  const int sw = l15 & 7;

  bf16x8 ones;
#pragma unroll
  for (int j = 0; j < 8; ++j) ones[j] = (bf16)1.0f;

  bf16x8 qf0[2], qf1[2];
#pragma unroll
  for (int kk = 0; kk < 2; ++kk) {
    qf0[kk] = *(const bf16x8*)(Qb + (long)(q0t * 64 + qloc) * 64 + kk * 32 +
                               quad * 8);
    qf1[kk] = *(const bf16x8*)(Qb + (long)(q1t * 64 + qloc) * 64 + kk * 32 +
                               quad * 8);
  }
  f32x4 acc0[4] = {}, acc1[4] = {};
  f32x4 accL0 = {}, accL1 = {};
  const f32x4 seedv = {SEXP_SEED, SEXP_SEED, SEXP_SEED, SEXP_SEED};

  for (int kt = 0; kt <= q1t; ++kt) {
#pragma unroll
    for (int it = 0; it < 2; ++it) {
      int chunk = it * 256 + tid;
      int r = chunk >> 3;
      int c = (((chunk & 7) ^ (r & 7)) << 3);
      int ldsbase = (it * 256 + wid * 64) * 16;
      async16(Kb + (long)(kt * 64 + r) * 64 + c, (char*)Ks + ldsbase);
      async16(Vb + (long)r * 2048 + kt * 64 + c, (char*)Vs + ldsbase);
    }
    __syncthreads();
    const bool dual = (kt <= q0t);  // block-uniform

    // ---- QK^T (S^T: lane l15 = q, key = mt*16+quad*4+r), shared kf ----
    f32x4 s1[4] = {seedv, seedv, seedv, seedv};
    f32x4 s0[4] = {seedv, seedv, seedv, seedv};
    if (dual) {
#pragma unroll
      for (int mt = 0; mt < 4; ++mt)
#pragma unroll
        for (int kk = 0; kk < 2; ++kk) {
          bf16x8 kf = *(const bf16x8*)(Ks + (mt * 16 + l15) * 64 +
                                       ((((kk << 2) + quad) ^ sw) << 3));
          s1[mt] = MFMA16(kf, qf1[kk], s1[mt]);
          s0[mt] = MFMA16(kf, qf0[kk], s0[mt]);
        }
    } else {
#pragma unroll
      for (int mt = 0; mt < 4; ++mt)
#pragma unroll
        for (int kk = 0; kk < 2; ++kk) {
          bf16x8 kf = *(const bf16x8*)(Ks + (mt * 16 + l15) * 64 +
                                       ((((kk << 2) + quad) ^ sw) << 3));
          s1[mt] = MFMA16(kf, qf1[kk], s1[mt]);
        }
    }
    if (kt == q1t) {  // diagonal of q1 (q1t > q0t -> single mode)
#pragma unroll
      for (int mt = 0; mt < 4; ++mt)
#pragma unroll
        for (int r = 0; r < 4; ++r)
          if ((mt * 16 + quad * 4 + r) > qloc) s1[mt][r] = 0.0f;
    }
    if (dual && kt == q0t) {
#pragma unroll
      for (int mt = 0; mt < 4; ++mt)
#pragma unroll
        for (int r = 0; r < 4; ++r)
          if ((mt * 16 + quad * 4 + r) > qloc) s0[mt][r] = 0.0f;
    }

    // ---- Schraudolph pack: bits = int(t'); bf16 = bits>>16 ----
#pragma unroll
    for (int mt = 0; mt < 4; ++mt) {
      int i0 = (int)s1[mt][0], i1 = (int)s1[mt][1];
      int i2 = (int)s1[mt][2], i3 = (int)s1[mt][3];
      uint2 pk;
      pk.x = __builtin_amdgcn_perm((unsigned)i1, (unsigned)i0, 0x07060302u);
      pk.y = __builtin_amdgcn_perm((unsigned)i3, (unsigned)i2, 0x07060302u);
      *(uint2*)(Pw1 + l15 * 88 + mt * 16 + quad * 4) = pk;
    }
    if (dual) {
#pragma unroll
      for (int mt = 0; mt < 4; ++mt) {
        int i0 = (int)s0[mt][0], i1 = (int)s0[mt][1];
        int i2 = (int)s0[mt][2], i3 = (int)s0[mt][3];
        uint2 pk;
        pk.x = __builtin_amdgcn_perm((unsigned)i1, (unsigned)i0, 0x07060302u);
        pk.y = __builtin_amdgcn_perm((unsigned)i3, (unsigned)i2, 0x07060302u);
        *(uint2*)(Pw0 + l15 * 88 + mt * 16 + quad * 4) = pk;
      }
    }
    asm volatile("s_waitcnt lgkmcnt(0)" ::: "memory");  // wave-private fence
    bf16x8 pf1[2], pf0[2];
#pragma unroll
    for (int kk = 0; kk < 2; ++kk)
      pf1[kk] = *(const bf16x8*)(Pw1 + l15 * 88 + kk * 32 + quad * 8);
    if (dual) {
#pragma unroll
      for (int kk = 0; kk < 2; ++kk)
        pf0[kk] = *(const bf16x8*)(Pw0 + l15 * 88 + kk * 32 + quad * 8);
    }

    // ---- PV, shared vf reads ----
    if (dual) {
#pragma unroll
      for (int nt = 0; nt < 4; ++nt)
#pragma unroll
        for (int kk = 0; kk < 2; ++kk) {
          bf16x8 vf = *(const bf16x8*)(Vs + (nt * 16 + l15) * 64 +
                                       ((((kk << 2) + quad) ^ sw) << 3));
          acc1[nt] = MFMA16(pf1[kk], vf, acc1[nt]);
          acc0[nt] = MFMA16(pf0[kk], vf, acc0[nt]);
        }
#pragma unroll
      for (int kk = 0; kk < 2; ++kk) {
        accL1 = MFMA16(pf1[kk], ones, accL1);
        accL0 = MFMA16(pf0[kk], ones, accL0);
      }
    } else {
#pragma unroll
      for (int nt = 0; nt < 4; ++nt)
#pragma unroll
        for (int kk = 0; kk < 2; ++kk) {
          bf16x8 vf = *(const bf16x8*)(Vs + (nt * 16 + l15) * 64 +
                                       ((((kk << 2) + quad) ^ sw) << 3));
          acc1[nt] = MFMA16(pf1[kk], vf, acc1[nt]);
        }
#pragma unroll
      for (int kk = 0; kk < 2; ++kk) accL1 = MFMA16(pf1[kk], ones, accL1);
    }
    __syncthreads();
  }

  // epilogue: accL rows aligned with accO rows -> no shuffles
  const int b = bh >> 4, h = bh & 15;
#pragma unroll
  for (int r = 0; r < 4; ++r) {
    float lr0 = 1.0f / accL0[r];
    float lr1 = 1.0f / accL1[r];
#pragma unroll
    for (int nt = 0; nt < 4; ++nt) {
      int d = h * 64 + nt * 16 + l15;
      int qg0 = q0t * 64 + wid * 16 + quad * 4 + r;
      int qg1 = q1t * 64 + wid * 16 + quad * 4 + r;
      Out[(long)(b * 2048 + qg0) * 1024 + d] = (bf16)(acc0[nt][r] * lr0);
      Out[(long)(b * 2048 + qg1) * 1024 + d] = (bf16)(acc1[nt][r] * lr1);
    }
  }
}

// ---------------------------------------------------------------------------
// Workspace layout (bytes):
//   xb  @ 0         (16,777,216)  -- reused as attn output
//   wqb @ 16777216  (2 MiB) \  [w_q; w_k] contiguous for fused QK GEMM,
//   wkb @ 18874368  (2 MiB) |  [w_v; w_o] follow for fused cast
//   wvb @ 20971520  (2 MiB) |
//   wob @ 23068672  (2 MiB) /
//   Qb  @ 25165824  (16,777,216)  (b,h,s,d) bf16, pre-scaled by QSCALE
//   Kb  @ 41943040  (16,777,216)  (b,h,s,d) bf16
//   VTb @ 58720256  (16,777,216)  (b,h,d,s) bf16
//   csT @ 75497472  (   524,288)  fused cos/sin float2 table
// ---------------------------------------------------------------------------
extern "C" void kernel_launch(void* const* d_in, const int* in_sizes, int n_in,
                              void* d_out, int out_size, void* d_ws,
                              size_t ws_size, hipStream_t stream) {
  const float* x = (const float*)d_in[0];
  const float* w_q = (const float*)d_in[1];
  const float* w_k = (const float*)d_in[2];
  const float* w_v = (const float*)d_in[3];
  const float* w_o = (const float*)d_in[4];
  const float* cosT = (const float*)d_in[5];
  const float* sinT = (const float*)d_in[6];

  char* ws = (char*)d_ws;
  bf16* xb = (bf16*)(ws + 0);
  bf16* wqb = (bf16*)(ws + 16777216);
  bf16* wvb = (bf16*)(ws + 20971520);
  bf16* wob = (bf16*)(ws + 23068672);
  bf16* Qb = (bf16*)(ws + 25165824);
  bf16* Kb = (bf16*)(ws + 41943040);
  bf16* VTb = (bf16*)(ws + 58720256);
  float2* csT = (float2*)(ws + 75497472);
  bf16* attnb = xb;

  // fused cast: x + all 4 weights + cos/sin float2 fusion in one launch
  cast_all_kernel<<<12544, 256, 0, stream>>>(x, w_q, w_k, w_v, w_o, cosT,
                                             sinT, xb, wqb, csT);

  // fused Q+K projection with RoPE (+Q Schraudolph pre-scale) -> (b,h,s,d)
  gemm_qk<<<dim3(16, 64), 256, 0, stream>>>(xb, wqb, Qb, csT, 1024);
  // V projection -> (b,h,d,s): A=w_v (M=1024), B=x (N=8192), 64x128 tiles
  gemm_tile<1, 64, 128><<<dim3(64, 16), 256, 0, stream>>>(wvb, xb, VTb, 8192,
                                                          1024);

  // balanced causal flash attention (fused dual step) -> (b,s,e) bf16
  attn_kernel<<<dim3(16, 64), 256, 0, stream>>>(Qb, Kb, VTb, attnb);

  // output projection -> fp32: A=attn (M=8192), B=w_o (N=1024), 128x64 tiles
  gemm_tile<2, 128, 64><<<dim3(16, 64), 256, 0, stream>>>(attnb, wob,
                                                          (float*)d_out, 1024,
                                                          1024);
}

// Round 7
// 294.105 us; speedup vs baseline: 1.0404x; 1.0404x over previous
//
#include <hip/hip_runtime.h>
#include <hip/hip_bf16.h>

// ---------------------------------------------------------------------------
// CausalMultiHeadedSelfAttention on gfx950.
// R7: attn reverted to R5 exactly (R6 dual-fusion spilled to scratch: WRITE
// 16->95 MB). GEMM LDS swizzle fixed 4-way -> 2-way (g(r)=(r>>1)&3, free per
// m136). Q/K projection and V projection merged into ONE launch (role by
// blockIdx parity) for tail overlap. Schraudolph P + MFMA-l kept.
// ---------------------------------------------------------------------------

typedef __bf16 bf16;
typedef __bf16 bf16x8 __attribute__((ext_vector_type(8)));
typedef __bf16 bf16x4 __attribute__((ext_vector_type(4)));
typedef float f32x4 __attribute__((ext_vector_type(4)));

#define LOG2E 1.4426950408889634f
// Schraudolph: p = exp(s/8 - 16) = 2^t, bits(p) ~= int(2^23*(t + 126.9427)).
// Q pre-scaled by QSCALE so QK-MFMA emits t' = 2^23*t; acc seeded with
// SEXP_SEED. t' in [7.7e8, 1.1e9]; masked entries t'=0 -> p=+0.0 exactly.
#define QSCALE (0.125f * LOG2E * 8388608.0f)
#define SEXP_SEED ((126.94269504f - 16.0f * LOG2E) * 8388608.0f)

__device__ __forceinline__ void async16(const void* g, void* l) {
  __builtin_amdgcn_global_load_lds(
      (const __attribute__((address_space(1))) void*)g,
      (__attribute__((address_space(3))) void*)l, 16, 0, 0);
}

#define MFMA16(a, b, c) __builtin_amdgcn_mfma_f32_16x16x32_bf16(a, b, c, 0, 0, 0)

// ---------------------------------------------------------------------------
// fused fp32 -> bf16 cast for x + 4 weights + cos/sin float2 fusion.
// ---------------------------------------------------------------------------
__global__ void cast_all_kernel(const float* __restrict__ x,
                                const float* __restrict__ wq,
                                const float* __restrict__ wk,
                                const float* __restrict__ wv,
                                const float* __restrict__ wo,
                                const float* __restrict__ cosT,
                                const float* __restrict__ sinT,
                                bf16* __restrict__ xb, bf16* __restrict__ wb,
                                float2* __restrict__ csT) {
  int i = blockIdx.x * blockDim.x + threadIdx.x;
  if (i >= 3145728) {  // cos/sin fusion: 65536 pairs
    int j = i - 3145728;
    float2 cs;
    cs.x = cosT[j];
    cs.y = sinT[j];
    csT[j] = cs;
    return;
  }
  const float* src;
  bf16* dst;
  long o;
  if (i < 2097152) {
    src = x; dst = xb; o = i;
  } else {
    long j = i - 2097152;
    int w = (int)(j >> 18);
    o = j & 262143;
    src = (w == 0) ? wq : (w == 1) ? wk : (w == 2) ? wv : wo;
    dst = wb + (long)w * 1048576;
  }
  float4 v = reinterpret_cast<const float4*>(src)[o];
  bf16x4 out;
  out.x = (bf16)v.x; out.y = (bf16)v.y; out.z = (bf16)v.z; out.w = (bf16)v.w;
  *reinterpret_cast<bf16x4*>(dst + o * 4) = out;
}

// ---------------------------------------------------------------------------
// Generic bt-GEMM body: C[m][n] = sum_k A[m][k]*B[n][k].  TM x TN block tile,
// BK=32.  LDS swizzle g(r)=(r>>1)&3 -> 2-way bank aliasing only (free).
// EPI 0: QK + RoPE epilogue (bn<8 = Q half, Schraudolph pre-scale).
// EPI 1: bf16 V^T (b,h,d,s).  EPI 2: fp32 row-major (M,N).
// ---------------------------------------------------------------------------
template <int EPI, int TM, int TN>
__device__ __forceinline__ void gemm_dev(const bf16* __restrict__ A,
                                         const bf16* __restrict__ B,
                                         void* __restrict__ C, int N, int K,
                                         int bm, int bn, bf16* As, bf16* Bs,
                                         const float2* __restrict__ csT) {
  constexpr int WM = TM / 64;
  constexpr int WN = 4 / WM;
  constexpr int CW = TN / WN;
  constexpr int NT = CW / 16;
  constexpr int ROUNDS = (TM + TN) / 64;
  const int tid = threadIdx.x;
  const int wid = tid >> 6, lane = tid & 63;
  const int quad = lane >> 4, l15 = lane & 15;
  const int waveM = wid / WN, waveN = wid % WN;

  f32x4 acc[4][NT] = {};
  const bf16* Ag = A + (long)bm * TM * K;
  const bf16* Bg = B + (long)bn * TN * K;

  for (int k0 = 0; k0 < K; k0 += 32) {
#pragma unroll
    for (int ri = 0; ri < ROUNDS; ++ri) {
      int c = ri * 256 + tid;
      int g = ri * 256 + (wid << 6);
      bool isA = g < TM * 4;
      int cl = isA ? c : c - TM * 4;
      int r = cl >> 2;
      int col = ((cl & 3) ^ ((r >> 1) & 3)) << 3;  // 2-way swizzle
      const bf16* src = (isA ? Ag : Bg) + (long)r * K + k0 + col;
      char* dst = isA ? ((char*)As + (long)g * 16)
                      : ((char*)Bs + (long)(g - TM * 4) * 16);
      async16(src, dst);
    }
    __syncthreads();
    bf16x8 af[4], bfr[NT];
#pragma unroll
    for (int t = 0; t < 4; ++t) {
      int rowA = waveM * 64 + t * 16 + l15;
      af[t] =
          *(const bf16x8*)(As + rowA * 32 + ((quad ^ ((rowA >> 1) & 3)) << 3));
    }
#pragma unroll
    for (int t = 0; t < NT; ++t) {
      int rowB = waveN * CW + t * 16 + l15;
      bfr[t] =
          *(const bf16x8*)(Bs + rowB * 32 + ((quad ^ ((rowB >> 1) & 3)) << 3));
    }
#pragma unroll
    for (int mt = 0; mt < 4; ++mt)
#pragma unroll
      for (int nt = 0; nt < NT; ++nt)
        acc[mt][nt] = MFMA16(af[mt], bfr[nt], acc[mt][nt]);
    __syncthreads();
  }

  const float qsc = (EPI == 0 && bn < 8) ? QSCALE : 1.0f;
#pragma unroll
  for (int mt = 0; mt < 4; ++mt)
#pragma unroll
    for (int nt = 0; nt < NT; ++nt)
#pragma unroll
      for (int r = 0; r < 4; ++r) {
        int row = bm * TM + waveM * 64 + mt * 16 + quad * 4 + r;
        int col = bn * TN + waveN * CW + nt * 16 + l15;
        float v = acc[mt][nt][r];
        if (EPI == 0) {
          // RoPE: col pairs (even,odd) live in adjacent lanes
          float pr = __shfl_xor(v, 1);
          int d = col & 63;
          float2 cs = csT[(row & 2047) * 32 + (d >> 1)];
          float o =
              (col & 1) ? (v * cs.x + pr * cs.y) : (v * cs.x - pr * cs.y);
          o *= qsc;
          long off = (long)(col >> 10) * 8388608 +
                     (long)(((row >> 11) << 4) + ((col >> 6) & 15)) * 131072 +
                     (long)(row & 2047) * 64 + d;
          ((bf16*)C)[off] = (bf16)o;
        } else if (EPI == 1) {
          long off = (long)(col >> 11) * 2097152 + (long)row * 2048 +
                     (col & 2047);
          ((bf16*)C)[off] = (bf16)v;
        } else {
          ((float*)C)[(long)row * N + col] = v;
        }
      }
}

// Merged Q/K projection (+RoPE) and V projection (V^T) in one launch.
// blockIdx.x parity selects role; 2048 blocks total (1024 each).
__global__ __launch_bounds__(256) void gemm_qkv(const bf16* __restrict__ xb,
                                                const bf16* __restrict__ wqk,
                                                const bf16* __restrict__ wv,
                                                bf16* __restrict__ QK,
                                                bf16* __restrict__ VT,
                                                const float2* __restrict__ csT) {
  __shared__ __align__(16) bf16 As[128 * 32];
  __shared__ __align__(16) bf16 Bs[128 * 32];
  int id = blockIdx.x >> 1;
  if (blockIdx.x & 1) {
    // V: A=w_v (M=1024), B=x (N=8192), 64x128 tiles, grid-equiv (64,16)
    gemm_dev<1, 64, 128>(wv, xb, VT, 8192, 1024, id >> 6, id & 63, As, Bs,
                         nullptr);
  } else {
    // QK: A=x (M=8192), B=[w_q;w_k] (N=2048), 128x128 tiles, grid-equiv (16,64)
    gemm_dev<0, 128, 128>(xb, wqk, QK, 2048, 1024, id >> 4, id & 15, As, Bs,
                          csT);
  }
}

// Output projection: A=attn (M=8192), B=w_o (N=1024), 128x64 tiles -> fp32.
__global__ __launch_bounds__(256) void gemm_out(const bf16* __restrict__ A,
                                                const bf16* __restrict__ B,
                                                float* __restrict__ C) {
  __shared__ __align__(16) bf16 As[128 * 32];
  __shared__ __align__(16) bf16 Bs[64 * 32];
  gemm_dev<2, 128, 64>(A, B, C, 1024, 1024, blockIdx.y, blockIdx.x, As, Bs,
                       nullptr);
}

// ---------------------------------------------------------------------------
// Flash attention, causal, paired q-tiles {p, 31-p}, R5 single-buffer
// structure (best measured).  Schraudolph P: QK MFMA seeded with SEXP_SEED
// emits t'; bf16 P bits = int(t')>>16 (1 cvt + 1/2 v_perm per elem).  l via
// MFMA with ones fragment -> accL rows align with accO rows (no shuffles).
// ---------------------------------------------------------------------------
__device__ __forceinline__ void attn_step(const bf16* Ks, const bf16* Vs,
                                          bf16* Pw, const bf16x8* qf,
                                          const bf16x8 ones, f32x4* accO,
                                          f32x4& accL, int quad, int l15,
                                          int qloc, bool diag) {
  const int sw = l15 & 7;
  const f32x4 seedv = {SEXP_SEED, SEXP_SEED, SEXP_SEED, SEXP_SEED};
  f32x4 sacc[4] = {seedv, seedv, seedv, seedv};
#pragma unroll
  for (int mt = 0; mt < 4; ++mt)
#pragma unroll
    for (int kk = 0; kk < 2; ++kk) {
      bf16x8 kf = *(const bf16x8*)(Ks + (mt * 16 + l15) * 64 +
                                   ((((kk << 2) + quad) ^ sw) << 3));
      sacc[mt] = MFMA16(kf, qf[kk], sacc[mt]);
    }
  // D layout: lane l15 = q (col), key_local = mt*16 + quad*4 + r (row)
  if (diag) {  // wave-uniform: mask -> t'=0 -> p=+0.0 exactly
#pragma unroll
    for (int mt = 0; mt < 4; ++mt)
#pragma unroll
      for (int r = 0; r < 4; ++r)
        if ((mt * 16 + quad * 4 + r) > qloc) sacc[mt][r] = 0.0f;
  }
  // Schraudolph exp2 + bf16 pack: bits = int(t'); bf16 = bits>>16
#pragma unroll
  for (int mt = 0; mt < 4; ++mt) {
    int i0 = (int)sacc[mt][0], i1 = (int)sacc[mt][1];
    int i2 = (int)sacc[mt][2], i3 = (int)sacc[mt][3];
    uint2 pk;
    pk.x = __builtin_amdgcn_perm((unsigned)i1, (unsigned)i0, 0x07060302u);
    pk.y = __builtin_amdgcn_perm((unsigned)i3, (unsigned)i2, 0x07060302u);
    *(uint2*)(Pw + l15 * 88 + mt * 16 + quad * 4) = pk;
  }
  asm volatile("s_waitcnt lgkmcnt(0)" ::: "memory");  // wave-private RAW fence
  bf16x8 pfr[2];
#pragma unroll
  for (int kk = 0; kk < 2; ++kk)
    pfr[kk] = *(const bf16x8*)(Pw + l15 * 88 + kk * 32 + quad * 8);
#pragma unroll
  for (int nt = 0; nt < 4; ++nt)
#pragma unroll
    for (int kk = 0; kk < 2; ++kk) {
      bf16x8 vf = *(const bf16x8*)(Vs + (nt * 16 + l15) * 64 +
                                   ((((kk << 2) + quad) ^ sw) << 3));
      accO[nt] = MFMA16(pfr[kk], vf, accO[nt]);
    }
#pragma unroll
  for (int kk = 0; kk < 2; ++kk)
    accL = MFMA16(pfr[kk], ones, accL);  // l[q=quad*4+r] = accL[r]
}

__global__ __launch_bounds__(256, 4) void attn_kernel(
    const bf16* __restrict__ Q, const bf16* __restrict__ Kg,
    const bf16* __restrict__ VT, bf16* __restrict__ Out) {
  __shared__ __align__(16) bf16 Ks[64 * 64];
  __shared__ __align__(16) bf16 Vs[64 * 64];
  __shared__ __align__(16) bf16 Ps[4][16 * 88];
  const int tid = threadIdx.x, wid = tid >> 6, lane = tid & 63;
  const int quad = lane >> 4, l15 = lane & 15;
  const int p = blockIdx.x, bh = blockIdx.y;
  const int q0t = p, q1t = 31 - p;
  const bf16* Qb = Q + (long)bh * 131072;
  const bf16* Kb = Kg + (long)bh * 131072;
  const bf16* Vb = VT + (long)bh * 131072;
  bf16* Pw = &Ps[wid][0];
  const int qloc = wid * 16 + l15;

  bf16x8 ones;
#pragma unroll
  for (int j = 0; j < 8; ++j) ones[j] = (bf16)1.0f;

  bf16x8 qf0[2], qf1[2];
#pragma unroll
  for (int kk = 0; kk < 2; ++kk) {
    qf0[kk] = *(const bf16x8*)(Qb + (long)(q0t * 64 + qloc) * 64 + kk * 32 +
                               quad * 8);
    qf1[kk] = *(const bf16x8*)(Qb + (long)(q1t * 64 + qloc) * 64 + kk * 32 +
                               quad * 8);
  }
  f32x4 acc0[4] = {}, acc1[4] = {};
  f32x4 accL0 = {}, accL1 = {};

  for (int kt = 0; kt <= q1t; ++kt) {
#pragma unroll
    for (int it = 0; it < 2; ++it) {
      int chunk = it * 256 + tid;
      int r = chunk >> 3;
      int c = (((chunk & 7) ^ (r & 7)) << 3);
      int ldsbase = (it * 256 + wid * 64) * 16;
      async16(Kb + (long)(kt * 64 + r) * 64 + c, (char*)Ks + ldsbase);
      async16(Vb + (long)r * 2048 + kt * 64 + c, (char*)Vs + ldsbase);
    }
    __syncthreads();
    attn_step(Ks, Vs, Pw, qf1, ones, acc1, accL1, quad, l15, qloc, kt == q1t);
    if (kt <= q0t)
      attn_step(Ks, Vs, Pw, qf0, ones, acc0, accL0, quad, l15, qloc,
                kt == q0t);
    __syncthreads();
  }

  // epilogue: accL rows already aligned with accO rows -> no shuffles
  const int b = bh >> 4, h = bh & 15;
#pragma unroll
  for (int r = 0; r < 4; ++r) {
    float lr0 = 1.0f / accL0[r];
    float lr1 = 1.0f / accL1[r];
#pragma unroll
    for (int nt = 0; nt < 4; ++nt) {
      int d = h * 64 + nt * 16 + l15;
      int qg0 = q0t * 64 + wid * 16 + quad * 4 + r;
      int qg1 = q1t * 64 + wid * 16 + quad * 4 + r;
      Out[(long)(b * 2048 + qg0) * 1024 + d] = (bf16)(acc0[nt][r] * lr0);
      Out[(long)(b * 2048 + qg1) * 1024 + d] = (bf16)(acc1[nt][r] * lr1);
    }
  }
}

// ---------------------------------------------------------------------------
// Workspace layout (bytes):
//   xb  @ 0         (16,777,216)  -- reused as attn output
//   wqb @ 16777216  (2 MiB) \  [w_q; w_k] contiguous for fused QK GEMM,
//   wkb @ 18874368  (2 MiB) |  [w_v; w_o] follow for fused cast
//   wvb @ 20971520  (2 MiB) |
//   wob @ 23068672  (2 MiB) /
//   Qb  @ 25165824  (16,777,216)  (b,h,s,d) bf16, pre-scaled by QSCALE
//   Kb  @ 41943040  (16,777,216)  (b,h,s,d) bf16
//   VTb @ 58720256  (16,777,216)  (b,h,d,s) bf16
//   csT @ 75497472  (   524,288)  fused cos/sin float2 table
// ---------------------------------------------------------------------------
extern "C" void kernel_launch(void* const* d_in, const int* in_sizes, int n_in,
                              void* d_out, int out_size, void* d_ws,
                              size_t ws_size, hipStream_t stream) {
  const float* x = (const float*)d_in[0];
  const float* w_q = (const float*)d_in[1];
  const float* w_k = (const float*)d_in[2];
  const float* w_v = (const float*)d_in[3];
  const float* w_o = (const float*)d_in[4];
  const float* cosT = (const float*)d_in[5];
  const float* sinT = (const float*)d_in[6];

  char* ws = (char*)d_ws;
  bf16* xb = (bf16*)(ws + 0);
  bf16* wqb = (bf16*)(ws + 16777216);
  bf16* wvb = (bf16*)(ws + 20971520);
  bf16* wob = (bf16*)(ws + 23068672);
  bf16* Qb = (bf16*)(ws + 25165824);
  bf16* Kb = (bf16*)(ws + 41943040);
  bf16* VTb = (bf16*)(ws + 58720256);
  float2* csT = (float2*)(ws + 75497472);
  bf16* attnb = xb;

  // fused cast: x + all 4 weights + cos/sin float2 fusion in one launch
  cast_all_kernel<<<12544, 256, 0, stream>>>(x, w_q, w_k, w_v, w_o, cosT,
                                             sinT, xb, wqb, csT);

  // merged Q/K projection (+RoPE, Schraudolph pre-scale) and V^T projection
  gemm_qkv<<<2048, 256, 0, stream>>>(xb, wqb, wvb, Qb, VTb, csT);

  // balanced causal flash attention -> (b,s,e) bf16
  attn_kernel<<<dim3(16, 64), 256, 0, stream>>>(Qb, Kb, VTb, attnb);

  // output projection -> fp32
  gemm_out<<<dim3(16, 64), 256, 0, stream>>>(attnb, wob, (float*)d_out);
}

// Round 8
// 279.522 us; speedup vs baseline: 1.0947x; 1.0522x over previous
//
#include <hip/hip_runtime.h>
#include <hip/hip_bf16.h>

// ---------------------------------------------------------------------------
// CausalMultiHeadedSelfAttention on gfx950.
// R8: qkv merge kept but role split by RANGE (id<1024 -> QK, else V) instead
// of parity: parity mapped each role to only 4 of 8 XCDs (round-robin
// blockIdx->XCD), serializing the halves (119us). Range split stripes both
// roles across all XCDs. 2-way LDS swizzle kept (verified conflicts -> 0).
// attn = R5 exact (best measured). Schraudolph P + MFMA-l kept.
// ---------------------------------------------------------------------------

typedef __bf16 bf16;
typedef __bf16 bf16x8 __attribute__((ext_vector_type(8)));
typedef __bf16 bf16x4 __attribute__((ext_vector_type(4)));
typedef float f32x4 __attribute__((ext_vector_type(4)));

#define LOG2E 1.4426950408889634f
// Schraudolph: p = exp(s/8 - 16) = 2^t, bits(p) ~= int(2^23*(t + 126.9427)).
// Q pre-scaled by QSCALE so QK-MFMA emits t' = 2^23*t; acc seeded with
// SEXP_SEED. t' in [7.7e8, 1.1e9]; masked entries t'=0 -> p=+0.0 exactly.
#define QSCALE (0.125f * LOG2E * 8388608.0f)
#define SEXP_SEED ((126.94269504f - 16.0f * LOG2E) * 8388608.0f)

__device__ __forceinline__ void async16(const void* g, void* l) {
  __builtin_amdgcn_global_load_lds(
      (const __attribute__((address_space(1))) void*)g,
      (__attribute__((address_space(3))) void*)l, 16, 0, 0);
}

#define MFMA16(a, b, c) __builtin_amdgcn_mfma_f32_16x16x32_bf16(a, b, c, 0, 0, 0)

// ---------------------------------------------------------------------------
// fused fp32 -> bf16 cast for x + 4 weights + cos/sin float2 fusion.
// ---------------------------------------------------------------------------
__global__ void cast_all_kernel(const float* __restrict__ x,
                                const float* __restrict__ wq,
                                const float* __restrict__ wk,
                                const float* __restrict__ wv,
                                const float* __restrict__ wo,
                                const float* __restrict__ cosT,
                                const float* __restrict__ sinT,
                                bf16* __restrict__ xb, bf16* __restrict__ wb,
                                float2* __restrict__ csT) {
  int i = blockIdx.x * blockDim.x + threadIdx.x;
  if (i >= 3145728) {  // cos/sin fusion: 65536 pairs
    int j = i - 3145728;
    float2 cs;
    cs.x = cosT[j];
    cs.y = sinT[j];
    csT[j] = cs;
    return;
  }
  const float* src;
  bf16* dst;
  long o;
  if (i < 2097152) {
    src = x; dst = xb; o = i;
  } else {
    long j = i - 2097152;
    int w = (int)(j >> 18);
    o = j & 262143;
    src = (w == 0) ? wq : (w == 1) ? wk : (w == 2) ? wv : wo;
    dst = wb + (long)w * 1048576;
  }
  float4 v = reinterpret_cast<const float4*>(src)[o];
  bf16x4 out;
  out.x = (bf16)v.x; out.y = (bf16)v.y; out.z = (bf16)v.z; out.w = (bf16)v.w;
  *reinterpret_cast<bf16x4*>(dst + o * 4) = out;
}

// ---------------------------------------------------------------------------
// Generic bt-GEMM body: C[m][n] = sum_k A[m][k]*B[n][k].  TM x TN block tile,
// BK=32.  LDS swizzle g(r)=(r>>1)&3 -> 2-way bank aliasing only (free;
// verified: SQ_LDS_BANK_CONFLICT 4.19M -> 0).
// EPI 0: QK + RoPE epilogue (bn<8 = Q half, Schraudolph pre-scale).
// EPI 1: bf16 V^T (b,h,d,s).  EPI 2: fp32 row-major (M,N).
// ---------------------------------------------------------------------------
template <int EPI, int TM, int TN>
__device__ __forceinline__ void gemm_dev(const bf16* __restrict__ A,
                                         const bf16* __restrict__ B,
                                         void* __restrict__ C, int N, int K,
                                         int bm, int bn, bf16* As, bf16* Bs,
                                         const float2* __restrict__ csT) {
  constexpr int WM = TM / 64;
  constexpr int WN = 4 / WM;
  constexpr int CW = TN / WN;
  constexpr int NT = CW / 16;
  constexpr int ROUNDS = (TM + TN) / 64;
  const int tid = threadIdx.x;
  const int wid = tid >> 6, lane = tid & 63;
  const int quad = lane >> 4, l15 = lane & 15;
  const int waveM = wid / WN, waveN = wid % WN;

  f32x4 acc[4][NT] = {};
  const bf16* Ag = A + (long)bm * TM * K;
  const bf16* Bg = B + (long)bn * TN * K;

  for (int k0 = 0; k0 < K; k0 += 32) {
#pragma unroll
    for (int ri = 0; ri < ROUNDS; ++ri) {
      int c = ri * 256 + tid;
      int g = ri * 256 + (wid << 6);
      bool isA = g < TM * 4;
      int cl = isA ? c : c - TM * 4;
      int r = cl >> 2;
      int col = ((cl & 3) ^ ((r >> 1) & 3)) << 3;  // 2-way swizzle
      const bf16* src = (isA ? Ag : Bg) + (long)r * K + k0 + col;
      char* dst = isA ? ((char*)As + (long)g * 16)
                      : ((char*)Bs + (long)(g - TM * 4) * 16);
      async16(src, dst);
    }
    __syncthreads();
    bf16x8 af[4], bfr[NT];
#pragma unroll
    for (int t = 0; t < 4; ++t) {
      int rowA = waveM * 64 + t * 16 + l15;
      af[t] =
          *(const bf16x8*)(As + rowA * 32 + ((quad ^ ((rowA >> 1) & 3)) << 3));
    }
#pragma unroll
    for (int t = 0; t < NT; ++t) {
      int rowB = waveN * CW + t * 16 + l15;
      bfr[t] =
          *(const bf16x8*)(Bs + rowB * 32 + ((quad ^ ((rowB >> 1) & 3)) << 3));
    }
#pragma unroll
    for (int mt = 0; mt < 4; ++mt)
#pragma unroll
      for (int nt = 0; nt < NT; ++nt)
        acc[mt][nt] = MFMA16(af[mt], bfr[nt], acc[mt][nt]);
    __syncthreads();
  }

  const float qsc = (EPI == 0 && bn < 8) ? QSCALE : 1.0f;
#pragma unroll
  for (int mt = 0; mt < 4; ++mt)
#pragma unroll
    for (int nt = 0; nt < NT; ++nt)
#pragma unroll
      for (int r = 0; r < 4; ++r) {
        int row = bm * TM + waveM * 64 + mt * 16 + quad * 4 + r;
        int col = bn * TN + waveN * CW + nt * 16 + l15;
        float v = acc[mt][nt][r];
        if (EPI == 0) {
          // RoPE: col pairs (even,odd) live in adjacent lanes
          float pr = __shfl_xor(v, 1);
          int d = col & 63;
          float2 cs = csT[(row & 2047) * 32 + (d >> 1)];
          float o =
              (col & 1) ? (v * cs.x + pr * cs.y) : (v * cs.x - pr * cs.y);
          o *= qsc;
          long off = (long)(col >> 10) * 8388608 +
                     (long)(((row >> 11) << 4) + ((col >> 6) & 15)) * 131072 +
                     (long)(row & 2047) * 64 + d;
          ((bf16*)C)[off] = (bf16)o;
        } else if (EPI == 1) {
          long off = (long)(col >> 11) * 2097152 + (long)row * 2048 +
                     (col & 2047);
          ((bf16*)C)[off] = (bf16)v;
        } else {
          ((float*)C)[(long)row * N + col] = v;
        }
      }
}

// Merged Q/K projection (+RoPE) and V projection (V^T) in one launch.
// RANGE role split: ids [0,1024) = QK (longer role, dispatched first),
// ids [1024,2048) = V.  Both roles stripe across all 8 XCDs.
__global__ __launch_bounds__(256) void gemm_qkv(const bf16* __restrict__ xb,
                                                const bf16* __restrict__ wqk,
                                                const bf16* __restrict__ wv,
                                                bf16* __restrict__ QK,
                                                bf16* __restrict__ VT,
                                                const float2* __restrict__ csT) {
  __shared__ __align__(16) bf16 As[128 * 32];
  __shared__ __align__(16) bf16 Bs[128 * 32];
  int id = blockIdx.x;
  if (id >= 1024) {
    // V: A=w_v (M=1024), B=x (N=8192), 64x128 tiles, grid-equiv (64,16)
    int v = id - 1024;
    gemm_dev<1, 64, 128>(wv, xb, VT, 8192, 1024, v >> 6, v & 63, As, Bs,
                         nullptr);
  } else {
    // QK: A=x (M=8192), B=[w_q;w_k] (N=2048), 128x128 tiles, grid-equiv (16,64)
    gemm_dev<0, 128, 128>(xb, wqk, QK, 2048, 1024, id >> 4, id & 15, As, Bs,
                          csT);
  }
}

// Output projection: A=attn (M=8192), B=w_o (N=1024), 128x64 tiles -> fp32.
__global__ __launch_bounds__(256) void gemm_out(const bf16* __restrict__ A,
                                                const bf16* __restrict__ B,
                                                float* __restrict__ C) {
  __shared__ __align__(16) bf16 As[128 * 32];
  __shared__ __align__(16) bf16 Bs[64 * 32];
  gemm_dev<2, 128, 64>(A, B, C, 1024, 1024, blockIdx.y, blockIdx.x, As, Bs,
                       nullptr);
}

// ---------------------------------------------------------------------------
// Flash attention, causal, paired q-tiles {p, 31-p}, R5 single-buffer
// structure (best measured).  Schraudolph P: QK MFMA seeded with SEXP_SEED
// emits t'; bf16 P bits = int(t')>>16 (1 cvt + 1/2 v_perm per elem).  l via
// MFMA with ones fragment -> accL rows align with accO rows (no shuffles).
// ---------------------------------------------------------------------------
__device__ __forceinline__ void attn_step(const bf16* Ks, const bf16* Vs,
                                          bf16* Pw, const bf16x8* qf,
                                          const bf16x8 ones, f32x4* accO,
                                          f32x4& accL, int quad, int l15,
                                          int qloc, bool diag) {
  const int sw = l15 & 7;
  const f32x4 seedv = {SEXP_SEED, SEXP_SEED, SEXP_SEED, SEXP_SEED};
  f32x4 sacc[4] = {seedv, seedv, seedv, seedv};
#pragma unroll
  for (int mt = 0; mt < 4; ++mt)
#pragma unroll
    for (int kk = 0; kk < 2; ++kk) {
      bf16x8 kf = *(const bf16x8*)(Ks + (mt * 16 + l15) * 64 +
                                   ((((kk << 2) + quad) ^ sw) << 3));
      sacc[mt] = MFMA16(kf, qf[kk], sacc[mt]);
    }
  // D layout: lane l15 = q (col), key_local = mt*16 + quad*4 + r (row)
  if (diag) {  // wave-uniform: mask -> t'=0 -> p=+0.0 exactly
#pragma unroll
    for (int mt = 0; mt < 4; ++mt)
#pragma unroll
      for (int r = 0; r < 4; ++r)
        if ((mt * 16 + quad * 4 + r) > qloc) sacc[mt][r] = 0.0f;
  }
  // Schraudolph exp2 + bf16 pack: bits = int(t'); bf16 = bits>>16
#pragma unroll
  for (int mt = 0; mt < 4; ++mt) {
    int i0 = (int)sacc[mt][0], i1 = (int)sacc[mt][1];
    int i2 = (int)sacc[mt][2], i3 = (int)sacc[mt][3];
    uint2 pk;
    pk.x = __builtin_amdgcn_perm((unsigned)i1, (unsigned)i0, 0x07060302u);
    pk.y = __builtin_amdgcn_perm((unsigned)i3, (unsigned)i2, 0x07060302u);
    *(uint2*)(Pw + l15 * 88 + mt * 16 + quad * 4) = pk;
  }
  asm volatile("s_waitcnt lgkmcnt(0)" ::: "memory");  // wave-private RAW fence
  bf16x8 pfr[2];
#pragma unroll
  for (int kk = 0; kk < 2; ++kk)
    pfr[kk] = *(const bf16x8*)(Pw + l15 * 88 + kk * 32 + quad * 8);
#pragma unroll
  for (int nt = 0; nt < 4; ++nt)
#pragma unroll
    for (int kk = 0; kk < 2; ++kk) {
      bf16x8 vf = *(const bf16x8*)(Vs + (nt * 16 + l15) * 64 +
                                   ((((kk << 2) + quad) ^ sw) << 3));
      accO[nt] = MFMA16(pfr[kk], vf, accO[nt]);
    }
#pragma unroll
  for (int kk = 0; kk < 2; ++kk)
    accL = MFMA16(pfr[kk], ones, accL);  // l[q=quad*4+r] = accL[r]
}

__global__ __launch_bounds__(256, 4) void attn_kernel(
    const bf16* __restrict__ Q, const bf16* __restrict__ Kg,
    const bf16* __restrict__ VT, bf16* __restrict__ Out) {
  __shared__ __align__(16) bf16 Ks[64 * 64];
  __shared__ __align__(16) bf16 Vs[64 * 64];
  __shared__ __align__(16) bf16 Ps[4][16 * 88];
  const int tid = threadIdx.x, wid = tid >> 6, lane = tid & 63;
  const int quad = lane >> 4, l15 = lane & 15;
  const int p = blockIdx.x, bh = blockIdx.y;
  const int q0t = p, q1t = 31 - p;
  const bf16* Qb = Q + (long)bh * 131072;
  const bf16* Kb = Kg + (long)bh * 131072;
  const bf16* Vb = VT + (long)bh * 131072;
  bf16* Pw = &Ps[wid][0];
  const int qloc = wid * 16 + l15;

  bf16x8 ones;
#pragma unroll
  for (int j = 0; j < 8; ++j) ones[j] = (bf16)1.0f;

  bf16x8 qf0[2], qf1[2];
#pragma unroll
  for (int kk = 0; kk < 2; ++kk) {
    qf0[kk] = *(const bf16x8*)(Qb + (long)(q0t * 64 + qloc) * 64 + kk * 32 +
                               quad * 8);
    qf1[kk] = *(const bf16x8*)(Qb + (long)(q1t * 64 + qloc) * 64 + kk * 32 +
                               quad * 8);
  }
  f32x4 acc0[4] = {}, acc1[4] = {};
  f32x4 accL0 = {}, accL1 = {};

  for (int kt = 0; kt <= q1t; ++kt) {
#pragma unroll
    for (int it = 0; it < 2; ++it) {
      int chunk = it * 256 + tid;
      int r = chunk >> 3;
      int c = (((chunk & 7) ^ (r & 7)) << 3);
      int ldsbase = (it * 256 + wid * 64) * 16;
      async16(Kb + (long)(kt * 64 + r) * 64 + c, (char*)Ks + ldsbase);
      async16(Vb + (long)r * 2048 + kt * 64 + c, (char*)Vs + ldsbase);
    }
    __syncthreads();
    attn_step(Ks, Vs, Pw, qf1, ones, acc1, accL1, quad, l15, qloc, kt == q1t);
    if (kt <= q0t)
      attn_step(Ks, Vs, Pw, qf0, ones, acc0, accL0, quad, l15, qloc,
                kt == q0t);
    __syncthreads();
  }

  // epilogue: accL rows already aligned with accO rows -> no shuffles
  const int b = bh >> 4, h = bh & 15;
#pragma unroll
  for (int r = 0; r < 4; ++r) {
    float lr0 = 1.0f / accL0[r];
    float lr1 = 1.0f / accL1[r];
#pragma unroll
    for (int nt = 0; nt < 4; ++nt) {
      int d = h * 64 + nt * 16 + l15;
      int qg0 = q0t * 64 + wid * 16 + quad * 4 + r;
      int qg1 = q1t * 64 + wid * 16 + quad * 4 + r;
      Out[(long)(b * 2048 + qg0) * 1024 + d] = (bf16)(acc0[nt][r] * lr0);
      Out[(long)(b * 2048 + qg1) * 1024 + d] = (bf16)(acc1[nt][r] * lr1);
    }
  }
}

// ---------------------------------------------------------------------------
// Workspace layout (bytes):
//   xb  @ 0         (16,777,216)  -- reused as attn output
//   wqb @ 16777216  (2 MiB) \  [w_q; w_k] contiguous for fused QK GEMM,
//   wkb @ 18874368  (2 MiB) |  [w_v; w_o] follow for fused cast
//   wvb @ 20971520  (2 MiB) |
//   wob @ 23068672  (2 MiB) /
//   Qb  @ 25165824  (16,777,216)  (b,h,s,d) bf16, pre-scaled by QSCALE
//   Kb  @ 41943040  (16,777,216)  (b,h,s,d) bf16
//   VTb @ 58720256  (16,777,216)  (b,h,d,s) bf16
//   csT @ 75497472  (   524,288)  fused cos/sin float2 table
// ---------------------------------------------------------------------------
extern "C" void kernel_launch(void* const* d_in, const int* in_sizes, int n_in,
                              void* d_out, int out_size, void* d_ws,
                              size_t ws_size, hipStream_t stream) {
  const float* x = (const float*)d_in[0];
  const float* w_q = (const float*)d_in[1];
  const float* w_k = (const float*)d_in[2];
  const float* w_v = (const float*)d_in[3];
  const float* w_o = (const float*)d_in[4];
  const float* cosT = (const float*)d_in[5];
  const float* sinT = (const float*)d_in[6];

  char* ws = (char*)d_ws;
  bf16* xb = (bf16*)(ws + 0);
  bf16* wqb = (bf16*)(ws + 16777216);
  bf16* wvb = (bf16*)(ws + 20971520);
  bf16* wob = (bf16*)(ws + 23068672);
  bf16* Qb = (bf16*)(ws + 25165824);
  bf16* Kb = (bf16*)(ws + 41943040);
  bf16* VTb = (bf16*)(ws + 58720256);
  float2* csT = (float2*)(ws + 75497472);
  bf16* attnb = xb;

  // fused cast: x + all 4 weights + cos/sin float2 fusion in one launch
  cast_all_kernel<<<12544, 256, 0, stream>>>(x, w_q, w_k, w_v, w_o, cosT,
                                             sinT, xb, wqb, csT);

  // merged Q/K (+RoPE, Schraudolph pre-scale) and V^T projections, range split
  gemm_qkv<<<2048, 256, 0, stream>>>(xb, wqb, wvb, Qb, VTb, csT);

  // balanced causal flash attention -> (b,s,e) bf16
  attn_kernel<<<dim3(16, 64), 256, 0, stream>>>(Qb, Kb, VTb, attnb);

  // output projection -> fp32
  gemm_out<<<dim3(16, 64), 256, 0, stream>>>(attnb, wob, (float*)d_out);
}